// Round 3
// baseline (646.214 us; speedup 1.0000x reference)
//
#include <hip/hip_runtime.h>

// ---------------- types / helpers ----------------
typedef __attribute__((ext_vector_type(8))) short bf16x8;           // MFMA A/B frag (8 bf16)
typedef __attribute__((ext_vector_type(8))) unsigned short ushort8; // 16B vector
typedef __attribute__((ext_vector_type(4))) float f32x4;            // MFMA C/D frag

#define NNODES 50000
#define NEDGES 160000
#define MP     50176   // 196*256 padded rows
#define NB_SCAN 196    // ceil(50000/256)

__device__ __forceinline__ float bf2f(unsigned short u) {
  return __uint_as_float(((unsigned int)u) << 16);
}
__device__ __forceinline__ unsigned short f2bf(float f) {
  unsigned int u = __float_as_uint(f);
  u += 0x7fffu + ((u >> 16) & 1u);   // RNE
  return (unsigned short)(u >> 16);
}
__device__ __forceinline__ void gld16(const void* g, void* l) {
  // async global->LDS, 16B per lane; LDS dest = wave-uniform base + lane*16
  __builtin_amdgcn_global_load_lds((__attribute__((address_space(1))) void*)g,
                                   (__attribute__((address_space(3))) void*)l, 16, 0, 0);
}

// ---------------- CSR build ----------------
__global__ void k_hist(const int* __restrict__ row, int* __restrict__ cnt, int n) {
  int i = blockIdx.x * 256 + threadIdx.x;
  if (i < n) atomicAdd(&cnt[row[i]], 1);
}

__global__ void k_block_reduce(const int* __restrict__ cnt, int* __restrict__ bsum, int n) {
  __shared__ int sd[256];
  int i = blockIdx.x * 256 + threadIdx.x;
  sd[threadIdx.x] = (i < n) ? cnt[i] : 0;
  __syncthreads();
  for (int o = 128; o > 0; o >>= 1) {
    if (threadIdx.x < o) sd[threadIdx.x] += sd[threadIdx.x + o];
    __syncthreads();
  }
  if (threadIdx.x == 0) bsum[blockIdx.x] = sd[0];
}

__global__ void k_scan_bsum(const int* __restrict__ bsum, int* __restrict__ boff, int nb,
                            int* __restrict__ rowptr, int n, int E) {
  __shared__ int sd[256];
  int v = (threadIdx.x < nb) ? bsum[threadIdx.x] : 0;
  sd[threadIdx.x] = v;
  __syncthreads();
  for (int o = 1; o < 256; o <<= 1) {
    int t = (threadIdx.x >= o) ? sd[threadIdx.x - o] : 0;
    __syncthreads();
    sd[threadIdx.x] += t;
    __syncthreads();
  }
  if (threadIdx.x < nb) boff[threadIdx.x] = sd[threadIdx.x] - v;  // exclusive
  if (threadIdx.x == 0) rowptr[n] = E;
}

__global__ void k_block_scan(const int* __restrict__ cnt, const int* __restrict__ boff,
                             int* __restrict__ rowptr, int* __restrict__ cursor, int n) {
  __shared__ int sd[256];
  int i = blockIdx.x * 256 + threadIdx.x;
  int v = (i < n) ? cnt[i] : 0;
  sd[threadIdx.x] = v;
  __syncthreads();
  for (int o = 1; o < 256; o <<= 1) {
    int t = (threadIdx.x >= o) ? sd[threadIdx.x - o] : 0;
    __syncthreads();
    sd[threadIdx.x] += t;
    __syncthreads();
  }
  if (i < n) {
    int r = boff[blockIdx.x] + sd[threadIdx.x] - v;  // exclusive
    rowptr[i] = r;
    cursor[i] = r;   // cursor aliases cnt; each thread reads its cnt before writing
  }
}

__global__ void k_scatter(const int* __restrict__ row, const int* __restrict__ col,
                          const float* __restrict__ val, int* __restrict__ cursor,
                          int* __restrict__ scol, float* __restrict__ sval, int n) {
  int e = blockIdx.x * 256 + threadIdx.x;
  if (e < n) {
    int p = atomicAdd(&cursor[row[e]], 1);
    scol[p] = col[e];
    sval[p] = val[e];
  }
}

// ---------------- packing ----------------
__global__ void k_cast_x(const float* __restrict__ x, unsigned short* __restrict__ xb, int nRealRows) {
  size_t idx = ((size_t)blockIdx.x * 256 + threadIdx.x) * 8;
  if (idx >= (size_t)MP * 1024) return;
  int row = (int)(idx >> 10);
  ushort8 o;
  if (row < nRealRows) {
    float4 a = *(const float4*)(x + idx);
    float4 b = *(const float4*)(x + idx + 4);
    o[0] = f2bf(a.x); o[1] = f2bf(a.y); o[2] = f2bf(a.z); o[3] = f2bf(a.w);
    o[4] = f2bf(b.x); o[5] = f2bf(b.y); o[6] = f2bf(b.z); o[7] = f2bf(b.w);
  } else {
    o = (ushort8){0,0,0,0,0,0,0,0};
  }
  *(ushort8*)(xb + idx) = o;
}

// dst[(dstOff+n)*K + k] = bf16(src[k*srcW + n])  (transpose-pack, K%32==0, nc%32==0)
__global__ void k_packT(const float* __restrict__ src, int K, int srcW, int nc,
                        unsigned short* __restrict__ dst, int dstOff) {
  __shared__ float tile[32][33];
  int k0 = blockIdx.x * 32, n0 = blockIdx.y * 32;
  int tx = threadIdx.x, ty = threadIdx.y;
  for (int i = ty; i < 32; i += 8)
    tile[i][tx] = src[(size_t)(k0 + i) * srcW + (n0 + tx)];
  __syncthreads();
  for (int i = ty; i < 32; i += 8)
    dst[(size_t)(dstOff + n0 + i) * K + (k0 + tx)] = f2bf(tile[tx][i]);
}

__global__ void k_pack_bias(const float* __restrict__ b1, const float* __restrict__ p1b,
                            const float* __restrict__ b2, const float* __restrict__ p2b,
                            float* __restrict__ bias1, float* __restrict__ bias2) {
  int t = threadIdx.x;
  bias1[t] = b1[t] + p1b[t];
  if (t < 64) bias2[t] = b2[t] + p2b[t];
}

// ---------------- big GEMM: 256x256 tile, BK=32, 4 LDS buffers, distance-3 prefetch ----------------
// C[M,N](bf16) = A[M,K](bf16) @ Bt[N,K]^T, f32 accum. M%256==0, N%256==0, K%128==0.
// LDS 128KB: 4 bufs x (A[256][32] @ +0, B[256][32] @ +16384). 16B chunks, swizzle chunk ^= (row>>1)&3.
// Counted vmcnt(8) at iter entry (never 0 in main loop) = T4; setprio around MFMA = T5.

__device__ __forceinline__ void rd4(bf16x8 (&f)[4], const char* smem, int off) {
#pragma unroll
  for (int i = 0; i < 4; ++i) f[i] = *(const bf16x8*)(smem + off + i * 1024);
}

__device__ __forceinline__ void cluster(f32x4 (&acc)[4][4], const bf16x8 (&a)[4], const bf16x8 (&b)[4]) {
#pragma unroll
  for (int m = 0; m < 4; ++m)
#pragma unroll
    for (int n = 0; n < 4; ++n)
      acc[m][n] = __builtin_amdgcn_mfma_f32_16x16x32_bf16(a[m], b[n], acc[m][n], 0, 0, 0);
}

__global__ __launch_bounds__(512, 1) void k_gemm256(
    const unsigned short* __restrict__ A, const unsigned short* __restrict__ Bt,
    unsigned short* __restrict__ C, int M, int N, int K) {
  extern __shared__ char smem[];
  const int NT = N >> 8;
  // bijective XCD swizzle (m204)
  const int nwg = gridDim.x;
  const int q = nwg >> 3, r = nwg & 7;
  const int xcd = blockIdx.x & 7, local = blockIdx.x >> 3;
  const int swz = (xcd < r ? xcd * (q + 1) : r * (q + 1) + (xcd - r) * q) + local;
  const int mt = swz / NT, nt = swz % NT;

  const int tid = threadIdx.x;
  const int w = tid >> 6, lane = tid & 63;
  const int wr = w >> 2, wc = w & 3;            // 2M x 4N waves; wave tile 128 x 64

  // staging: thread -> (row = tid>>2 [+128], chunk = tid&3), source chunk pre-swizzled
  const int srow = tid >> 2, c0 = tid & 3;
  const int schunk = c0 ^ ((srow >> 1) & 3);
  const unsigned short* gA = A + (size_t)(mt * 256 + srow) * K + schunk * 8;
  const unsigned short* gB = Bt + (size_t)(nt * 256 + srow) * K + schunk * 8;
  const size_t rs = (size_t)128 * K;
  const int wb = w << 10;   // wave-uniform LDS dest base offset

  // ds_read bases: frag lane reads row (..+lane&15), k-chunk (lane>>4), swizzled
  const int l15 = lane & 15;
  const int cpos = ((lane >> 4) ^ ((l15 >> 1) & 3)) << 4;
  const int aOff = (wr * 128 + l15) * 64 + cpos;            // + m*1024
  const int bOff = 16384 + (wc * 64 + l15) * 64 + cpos;     // + n*1024

  f32x4 accLo[4][4] = {}, accHi[4][4] = {};
  const int T = K >> 5;

  auto STAGE = [&](int t) {
    char* base = smem + ((t & 3) << 15);
    const unsigned short* a = gA + t * 32;
    const unsigned short* b = gB + t * 32;
    gld16(a, base + wb);
    gld16(a + rs, base + 8192 + wb);
    gld16(b, base + 16384 + wb);
    gld16(b + rs, base + 24576 + wb);
  };

#define KITER(T_, WSTR, DOSTAGE) { \
    const int bb = ((T_) & 3) << 15; \
    asm volatile("s_waitcnt vmcnt(" WSTR ")" ::: "memory"); \
    __builtin_amdgcn_sched_barrier(0); \
    __builtin_amdgcn_s_barrier(); \
    __builtin_amdgcn_sched_barrier(0); \
    bf16x8 af[4], bfr[4]; \
    rd4(af, smem, bb + aOff); \
    rd4(bfr, smem, bb + bOff); \
    if (DOSTAGE) STAGE((T_) + 3); \
    __builtin_amdgcn_s_barrier(); \
    __builtin_amdgcn_s_setprio(1); \
    cluster(accLo, af, bfr); \
    __builtin_amdgcn_s_setprio(0); \
    __builtin_amdgcn_s_barrier(); \
    rd4(af, smem, bb + aOff + 4096); \
    __builtin_amdgcn_s_setprio(1); \
    cluster(accHi, af, bfr); \
    __builtin_amdgcn_s_setprio(0); \
    __builtin_amdgcn_sched_barrier(0); \
  }

  // prologue: distance-3 prefetch
  STAGE(0); STAGE(1); STAGE(2);
  for (int t = 0; t < T - 3; ++t) KITER(t, "8", true)
  KITER(T - 3, "8", false)
  KITER(T - 2, "4", false)
  KITER(T - 1, "0", false)
#undef KITER

  // epilogue
  const int r0 = mt * 256 + wr * 128 + (lane >> 4) * 4;
  const int c0e = nt * 256 + wc * 64 + l15;
#pragma unroll
  for (int m = 0; m < 4; ++m)
#pragma unroll
    for (int n = 0; n < 4; ++n)
#pragma unroll
      for (int j = 0; j < 4; ++j) {
        C[(size_t)(r0 + m * 16 + j) * N + (c0e + n * 16)] = f2bf(accLo[m][n][j]);
        C[(size_t)(r0 + 64 + m * 16 + j) * N + (c0e + n * 16)] = f2bf(accHi[m][n][j]);
      }
}

// ---------------- small GEMM (final layer, N=128): 128x128 tile, BK=32, 4 waves ----------------
__global__ __launch_bounds__(256) void k_gemm_bt(
    const unsigned short* __restrict__ A, const unsigned short* __restrict__ Bt,
    unsigned short* __restrict__ C, int M, int N, int K) {
  __shared__ __align__(16) unsigned short As[128 * 32];
  __shared__ __align__(16) unsigned short Bs[128 * 32];
  const int ntc = N >> 7;
  const int mt = blockIdx.x / ntc;
  const int nt = blockIdx.x % ntc;
  const int t = threadIdx.x;
  const int w = t >> 6, lane = t & 63;
  const int wr = w >> 1, wc = w & 1;
  f32x4 acc[4][4] = {};
  const unsigned short* ga = A + (size_t)(mt * 128 + (t >> 2)) * K + (t & 3) * 8;
  const unsigned short* gb = Bt + (size_t)(nt * 128 + (t >> 2)) * K + (t & 3) * 8;
  unsigned short* lA = &As[w * 512];
  unsigned short* lB = &Bs[w * 512];
  const size_t rowskip = (size_t)64 * K;
  for (int kt = 0; kt < K; kt += 32) {
    gld16(ga + kt, lA);
    gld16(ga + kt + rowskip, lA + 2048);
    gld16(gb + kt, lB);
    gld16(gb + kt + rowskip, lB + 2048);
    __syncthreads();
    bf16x8 af[4], bfr[4];
#pragma unroll
    for (int m = 0; m < 4; ++m)
      af[m] = *(const bf16x8*)&As[(wr * 64 + m * 16 + (lane & 15)) * 32 + (lane >> 4) * 8];
#pragma unroll
    for (int n = 0; n < 4; ++n)
      bfr[n] = *(const bf16x8*)&Bs[(wc * 64 + n * 16 + (lane & 15)) * 32 + (lane >> 4) * 8];
#pragma unroll
    for (int m = 0; m < 4; ++m)
#pragma unroll
      for (int n = 0; n < 4; ++n)
        acc[m][n] = __builtin_amdgcn_mfma_f32_16x16x32_bf16(af[m], bfr[n], acc[m][n], 0, 0, 0);
    __syncthreads();
  }
  const int r0 = mt * 128 + wr * 64 + (lane >> 4) * 4;
  const int c0 = nt * 128 + wc * 64 + (lane & 15);
#pragma unroll
  for (int m = 0; m < 4; ++m)
#pragma unroll
    for (int n = 0; n < 4; ++n)
#pragma unroll
      for (int r = 0; r < 4; ++r)
        C[(size_t)(r0 + m * 16 + r) * N + (c0 + n * 16)] = f2bf(acc[m][n][r]);
}

// ---------------- SpMM + epilogue (512 feat): out = relu(sum val*s[col] + bias + res) ----------------
__global__ __launch_bounds__(256) void k_spmm_ep512(
    const int* __restrict__ rowptr, const int* __restrict__ scol, const float* __restrict__ sval,
    const unsigned short* __restrict__ s, int sStride,
    const unsigned short* __restrict__ res, int resStride,
    const float* __restrict__ bias,
    unsigned short* __restrict__ o, int oStride, int nReal, int nTot) {
  int gw = (blockIdx.x * 256 + threadIdx.x) >> 6;
  int lane = threadIdx.x & 63;
  if (gw >= nTot) return;
  unsigned short* op = o + (size_t)gw * oStride + lane * 8;
  if (gw >= nReal) {  // keep pad rows zero for next GEMM's A reads
    *(ushort8*)op = (ushort8){0,0,0,0,0,0,0,0};
    return;
  }
  float acc[8] = {0.f,0.f,0.f,0.f,0.f,0.f,0.f,0.f};
  int e0 = rowptr[gw], e1 = rowptr[gw + 1];
  for (int e = e0; e < e1; ++e) {
    int c = scol[e];
    float v = sval[e];
    ushort8 svv = *(const ushort8*)(s + (size_t)c * sStride + lane * 8);
#pragma unroll
    for (int k = 0; k < 8; ++k) acc[k] += v * bf2f(svv[k]);
  }
  ushort8 rv = *(const ushort8*)(res + (size_t)gw * resStride + lane * 8);
  ushort8 ov;
#pragma unroll
  for (int k = 0; k < 8; ++k) {
    float tt = acc[k] + bias[lane * 8 + k] + bf2f(rv[k]);
    ov[k] = f2bf(fmaxf(tt, 0.f));
  }
  *(ushort8*)op = ov;
}

// ---------------- final: 64-wide SpMM + bias + res + relu + log_softmax ----------------
__global__ __launch_bounds__(256) void k_spmm_lsm(
    const int* __restrict__ rowptr, const int* __restrict__ scol, const float* __restrict__ sval,
    const unsigned short* __restrict__ g2, const float* __restrict__ bias2,
    float* __restrict__ out, int n) {
  int gw = (blockIdx.x * 256 + threadIdx.x) >> 6;
  int lane = threadIdx.x & 63;
  if (gw >= n) return;
  int e0 = rowptr[gw], e1 = rowptr[gw + 1];
  float acc = 0.f;
  for (int e = e0; e < e1; ++e) {
    int c = scol[e];
    acc += sval[e] * bf2f(g2[(size_t)c * 128 + lane]);
  }
  float t = acc + bias2[lane] + bf2f(g2[(size_t)gw * 128 + 64 + lane]);
  float v = fmaxf(t, 0.f);
  float m = v;
#pragma unroll
  for (int o = 32; o > 0; o >>= 1) m = fmaxf(m, __shfl_xor(m, o));
  float ex = __expf(v - m);
  float ss = ex;
#pragma unroll
  for (int o = 32; o > 0; o >>= 1) ss += __shfl_xor(ss, o);
  out[(size_t)gw * 64 + lane] = v - m - __logf(ss);
}

// ---------------- launch ----------------
extern "C" void kernel_launch(void* const* d_in, const int* in_sizes, int n_in,
                              void* d_out, int out_size, void* d_ws, size_t ws_size,
                              hipStream_t stream) {
  const float* x    = (const float*)d_in[0];
  const int*   arow = (const int*)d_in[1];
  const int*   acol = (const int*)d_in[2];
  const float* aval = (const float*)d_in[3];
  const float* W1   = (const float*)d_in[4];
  const float* b1   = (const float*)d_in[5];
  const float* p1W  = (const float*)d_in[6];
  const float* p1b  = (const float*)d_in[7];
  const float* W3   = (const float*)d_in[8];
  const float* b3   = (const float*)d_in[9];
  const float* W2   = (const float*)d_in[10];
  const float* b2   = (const float*)d_in[11];
  const float* p2W  = (const float*)d_in[12];
  const float* p2b  = (const float*)d_in[13];
  float* out = (float*)d_out;

  char* wsp = (char*)d_ws;
  size_t off = 0;
  auto take = [&](size_t bytes) -> char* {
    char* p = wsp + off;
    off = (off + bytes + 255) & ~(size_t)255;
    return p;
  };
  unsigned short* xb  = (unsigned short*)take((size_t)MP * 1024 * 2);
  unsigned short* g1  = (unsigned short*)take((size_t)MP * 1024 * 2);
  unsigned short* B1t = (unsigned short*)take((size_t)1024 * 1024 * 2);
  unsigned short* W3t = (unsigned short*)take((size_t)512 * 512 * 2);
  unsigned short* B2t = (unsigned short*)take((size_t)128 * 512 * 2);
  float* bias1 = (float*)take(512 * 4);
  float* bias2 = (float*)take(64 * 4);
  int*   cnt    = (int*)take((size_t)NNODES * 4);   // reused as cursor
  int*   rowptr = (int*)take((size_t)(NNODES + 1) * 4);
  int*   bsum   = (int*)take(256 * 4);
  int*   boff   = (int*)take(256 * 4);
  int*   scol   = (int*)take((size_t)NEDGES * 4);
  float* sval   = (float*)take((size_t)NEDGES * 4);
  unsigned short* h  = xb;  // alias: xb dead after GEMM1
  unsigned short* s  = g1;  // alias: g1 dead after layer-1 SpMM
  unsigned short* g2 = g1;  // alias: s dead after last L3 SpMM

  // CSR build
  hipMemsetAsync(cnt, 0, (size_t)NNODES * 4, stream);
  k_hist<<<(NEDGES + 255) / 256, 256, 0, stream>>>(arow, cnt, NEDGES);
  k_block_reduce<<<NB_SCAN, 256, 0, stream>>>(cnt, bsum, NNODES);
  k_scan_bsum<<<1, 256, 0, stream>>>(bsum, boff, NB_SCAN, rowptr, NNODES, NEDGES);
  k_block_scan<<<NB_SCAN, 256, 0, stream>>>(cnt, boff, rowptr, cnt, NNODES);
  k_scatter<<<(NEDGES + 255) / 256, 256, 0, stream>>>(arow, acol, aval, cnt, scol, sval, NEDGES);

  // pack inputs
  k_cast_x<<<(int)(((size_t)MP * 1024 / 8 + 255) / 256), 256, 0, stream>>>(x, xb, NNODES);
  k_packT<<<dim3(1024 / 32, 512 / 32), dim3(32, 8), 0, stream>>>(W1, 1024, 512, 512, B1t, 0);
  k_packT<<<dim3(1024 / 32, 512 / 32), dim3(32, 8), 0, stream>>>(p1W, 1024, 512, 512, B1t, 512);
  k_packT<<<dim3(512 / 32, 512 / 32), dim3(32, 8), 0, stream>>>(W3, 512, 512, 512, W3t, 0);
  k_packT<<<dim3(512 / 32, 64 / 32), dim3(32, 8), 0, stream>>>(W2, 512, 64, 64, B2t, 0);
  k_packT<<<dim3(512 / 32, 64 / 32), dim3(32, 8), 0, stream>>>(p2W, 512, 64, 64, B2t, 64);
  k_pack_bias<<<1, 512, 0, stream>>>(b1, p1b, b2, p2b, bias1, bias2);

  // layer 1: g1 = [x@W1 | x@p1W] ; h = relu(spmm + b1 + res + p1b)
  k_gemm256<<<196 * 4, 512, 131072, stream>>>(xb, B1t, g1, MP, 1024, 1024);
  k_spmm_ep512<<<MP / 4, 256, 0, stream>>>(rowptr, scol, sval, g1, 1024, g1 + 512, 1024,
                                           bias1, h, 512, NNODES, MP);
  // 4 x gc3 (shared W3): s = h@W3 ; h = relu(spmm + b3 + h)
  for (int i = 0; i < 4; ++i) {
    k_gemm256<<<196 * 2, 512, 131072, stream>>>(h, W3t, s, MP, 512, 512);
    k_spmm_ep512<<<MP / 4, 256, 0, stream>>>(rowptr, scol, sval, s, 512, h, 512,
                                             b3, h, 512, NNODES, MP);
  }
  // final: g2 = [h@W2 | h@p2W] ; out = log_softmax(relu(spmm + b2 + res + p2b))
  k_gemm_bt<<<MP / 128, 256, 0, stream>>>(h, B2t, g2, MP, 128, 512);
  k_spmm_lsm<<<(NNODES + 3) / 4, 256, 0, stream>>>(rowptr, scol, sval, g2, bias2, out, NNODES);
}

// Round 4
// 630.534 us; speedup vs baseline: 1.0249x; 1.0249x over previous
//
#include <hip/hip_runtime.h>

// ---------------- types / helpers ----------------
typedef __attribute__((ext_vector_type(8))) short bf16x8;           // MFMA A/B frag (8 bf16)
typedef __attribute__((ext_vector_type(8))) unsigned short ushort8; // 16B vector
typedef __attribute__((ext_vector_type(4))) float f32x4;            // MFMA C/D frag

#define NNODES 50000
#define NEDGES 160000
#define MP     50176   // 196*256 padded rows
#define NB_SCAN 196    // ceil(50000/256)

__device__ __forceinline__ float bf2f(unsigned short u) {
  return __uint_as_float(((unsigned int)u) << 16);
}
__device__ __forceinline__ unsigned short f2bf(float f) {
  unsigned int u = __float_as_uint(f);
  u += 0x7fffu + ((u >> 16) & 1u);   // RNE
  return (unsigned short)(u >> 16);
}
__device__ __forceinline__ void gld16(const void* g, void* l) {
  // async global->LDS, 16B per lane; LDS dest = wave-uniform base + lane*16
  __builtin_amdgcn_global_load_lds((__attribute__((address_space(1))) void*)g,
                                   (__attribute__((address_space(3))) void*)l, 16, 0, 0);
}

// ---------------- CSR build ----------------
__global__ void k_hist(const int* __restrict__ row, int* __restrict__ cnt, int n) {
  int i = blockIdx.x * 256 + threadIdx.x;
  if (i < n) atomicAdd(&cnt[row[i]], 1);
}

__global__ void k_block_reduce(const int* __restrict__ cnt, int* __restrict__ bsum, int n) {
  __shared__ int sd[256];
  int i = blockIdx.x * 256 + threadIdx.x;
  sd[threadIdx.x] = (i < n) ? cnt[i] : 0;
  __syncthreads();
  for (int o = 128; o > 0; o >>= 1) {
    if (threadIdx.x < o) sd[threadIdx.x] += sd[threadIdx.x + o];
    __syncthreads();
  }
  if (threadIdx.x == 0) bsum[blockIdx.x] = sd[0];
}

__global__ void k_scan_bsum(const int* __restrict__ bsum, int* __restrict__ boff, int nb,
                            int* __restrict__ rowptr, int n, int E) {
  __shared__ int sd[256];
  int v = (threadIdx.x < nb) ? bsum[threadIdx.x] : 0;
  sd[threadIdx.x] = v;
  __syncthreads();
  for (int o = 1; o < 256; o <<= 1) {
    int t = (threadIdx.x >= o) ? sd[threadIdx.x - o] : 0;
    __syncthreads();
    sd[threadIdx.x] += t;
    __syncthreads();
  }
  if (threadIdx.x < nb) boff[threadIdx.x] = sd[threadIdx.x] - v;  // exclusive
  if (threadIdx.x == 0) rowptr[n] = E;
}

__global__ void k_block_scan(const int* __restrict__ cnt, const int* __restrict__ boff,
                             int* __restrict__ rowptr, int* __restrict__ cursor, int n) {
  __shared__ int sd[256];
  int i = blockIdx.x * 256 + threadIdx.x;
  int v = (i < n) ? cnt[i] : 0;
  sd[threadIdx.x] = v;
  __syncthreads();
  for (int o = 1; o < 256; o <<= 1) {
    int t = (threadIdx.x >= o) ? sd[threadIdx.x - o] : 0;
    __syncthreads();
    sd[threadIdx.x] += t;
    __syncthreads();
  }
  if (i < n) {
    int r = boff[blockIdx.x] + sd[threadIdx.x] - v;  // exclusive
    rowptr[i] = r;
    cursor[i] = r;   // cursor aliases cnt; each thread reads its cnt before writing
  }
}

__global__ void k_scatter(const int* __restrict__ row, const int* __restrict__ col,
                          const float* __restrict__ val, int* __restrict__ cursor,
                          int* __restrict__ scol, float* __restrict__ sval, int n) {
  int e = blockIdx.x * 256 + threadIdx.x;
  if (e < n) {
    int p = atomicAdd(&cursor[row[e]], 1);
    scol[p] = col[e];
    sval[p] = val[e];
  }
}

// ---------------- packing ----------------
__global__ void k_cast_x(const float* __restrict__ x, unsigned short* __restrict__ xb, int nRealRows) {
  size_t idx = ((size_t)blockIdx.x * 256 + threadIdx.x) * 8;
  if (idx >= (size_t)MP * 1024) return;
  int row = (int)(idx >> 10);
  ushort8 o;
  if (row < nRealRows) {
    float4 a = *(const float4*)(x + idx);
    float4 b = *(const float4*)(x + idx + 4);
    o[0] = f2bf(a.x); o[1] = f2bf(a.y); o[2] = f2bf(a.z); o[3] = f2bf(a.w);
    o[4] = f2bf(b.x); o[5] = f2bf(b.y); o[6] = f2bf(b.z); o[7] = f2bf(b.w);
  } else {
    o = (ushort8){0,0,0,0,0,0,0,0};
  }
  *(ushort8*)(xb + idx) = o;
}

// dst[(dstOff+n)*K + k] = bf16(src[k*srcW + n])  (transpose-pack, K%32==0, nc%32==0)
__global__ void k_packT(const float* __restrict__ src, int K, int srcW, int nc,
                        unsigned short* __restrict__ dst, int dstOff) {
  __shared__ float tile[32][33];
  int k0 = blockIdx.x * 32, n0 = blockIdx.y * 32;
  int tx = threadIdx.x, ty = threadIdx.y;
  for (int i = ty; i < 32; i += 8)
    tile[i][tx] = src[(size_t)(k0 + i) * srcW + (n0 + tx)];
  __syncthreads();
  for (int i = ty; i < 32; i += 8)
    dst[(size_t)(dstOff + n0 + i) * K + (k0 + tx)] = f2bf(tile[tx][i]);
}

__global__ void k_pack_bias(const float* __restrict__ b1, const float* __restrict__ p1b,
                            const float* __restrict__ b2, const float* __restrict__ p2b,
                            float* __restrict__ bias1, float* __restrict__ bias2) {
  int t = threadIdx.x;
  bias1[t] = b1[t] + p1b[t];
  if (t < 64) bias2[t] = b2[t] + p2b[t];
}

// ---------------- big GEMM: 256x256 tile, BK=32, 3 LDS buffers, distance-2, 4 sub-phases ----------------
// C[M,N](bf16) = A[M,K](bf16) @ Bt[N,K]^T, f32 accum. M%256==0, N%256==0, K%32==0, K/32>=3.
// LDS 96KB: buf t%3 (32KB) = A[256][32] @ +0, B[256][32] @ +16384; 16B chunks, chunk ^= (row>>1)&3.
// Per tile: vmcnt(4) (counted: leaves t+1's 4 units in flight) + barrier, then 4 phases
// {2 ds_read A-frags (+4 B in ph0); 1 stage-unit for t+2; setprio+8 MFMA; barrier}.

__device__ __forceinline__ void mfma8(f32x4* accA, f32x4* accB,
                                      bf16x8 a0, bf16x8 a1, const bf16x8* bfr) {
#pragma unroll
  for (int n = 0; n < 4; ++n)
    accA[n] = __builtin_amdgcn_mfma_f32_16x16x32_bf16(a0, bfr[n], accA[n], 0, 0, 0);
#pragma unroll
  for (int n = 0; n < 4; ++n)
    accB[n] = __builtin_amdgcn_mfma_f32_16x16x32_bf16(a1, bfr[n], accB[n], 0, 0, 0);
}

__global__ __launch_bounds__(512, 1) void k_gemm256(
    const unsigned short* __restrict__ A, const unsigned short* __restrict__ Bt,
    unsigned short* __restrict__ C, int M, int N, int K) {
  extern __shared__ char smem[];
  const int NT = N >> 8;
  // bijective XCD swizzle (m204)
  const int nwg = gridDim.x;
  const int q = nwg >> 3, r = nwg & 7;
  const int xcd = blockIdx.x & 7, local = blockIdx.x >> 3;
  const int swz = (xcd < r ? xcd * (q + 1) : r * (q + 1) + (xcd - r) * q) + local;
  const int mt = swz / NT, nt = swz % NT;

  const int tid = threadIdx.x;
  const int w = tid >> 6, lane = tid & 63;
  const int wr = w >> 2, wc = w & 3;            // 2M x 4N waves; wave tile 128 x 64

  // staging: unit = 128 rows (8KB = 512 thr x 16B). lane l of wave w covers
  // row = w*16 + (l>>2), LDS chunk = l&3; source chunk inverse-swizzled.
  const int srow = w * 16 + (lane >> 2);
  const int schunk = (lane & 3) ^ ((lane >> 3) & 3);
  const unsigned short* gA = A + (size_t)(mt * 256 + srow) * K + schunk * 8;
  const unsigned short* gB = Bt + (size_t)(nt * 256 + srow) * K + schunk * 8;
  const size_t rs128 = (size_t)128 * K;
  const int wb = w << 10;   // wave-uniform LDS dest offset within unit

  // ds_read bases: frag row = base + (lane&15), k-chunk = lane>>4, swizzled by (row>>1)&3
  const int l15 = lane & 15;
  const int cpos = ((lane >> 4) ^ ((l15 >> 1) & 3)) << 4;
  const int aOff = (wr * 128 + l15) * 64 + cpos;            // + m*1024
  const int bOff = 16384 + (wc * 64 + l15) * 64 + cpos;     // + n*1024

  f32x4 acc[8][4] = {};
  const int T = K >> 5;

  auto stage_u = [&](int t, int u) {
    // u: 0 = A rows 0-127, 1 = A rows 128-255, 2 = B rows 0-127, 3 = B rows 128-255
    char* dst = smem + (t % 3) * 32768 + u * 8192 + wb;
    const unsigned short* g = (u < 2 ? gA : gB) + ((u & 1) ? rs128 : 0) + (size_t)t * 32;
    gld16(g, dst);
  };

  // prologue: tiles 0 and 1 fully staged (8 outstanding units)
#pragma unroll
  for (int u = 0; u < 4; ++u) stage_u(0, u);
#pragma unroll
  for (int u = 0; u < 4; ++u) stage_u(1, u);

  for (int t = 0; t < T; ++t) {
    const int bb = (t % 3) * 32768;
    if (t < T - 1) asm volatile("s_waitcnt vmcnt(4)" ::: "memory");
    else           asm volatile("s_waitcnt vmcnt(0)" ::: "memory");
    __builtin_amdgcn_s_barrier();
    const bool st = t < T - 2;
    bf16x8 bfr[4], a0, a1;
    // ---- phase 0: B n0-3 + A m0-1; stage A-unit0(t+2); mfma m0-1
#pragma unroll
    for (int n = 0; n < 4; ++n) bfr[n] = *(const bf16x8*)(smem + bb + bOff + n * 1024);
    a0 = *(const bf16x8*)(smem + bb + aOff);
    a1 = *(const bf16x8*)(smem + bb + aOff + 1024);
    if (st) stage_u(t + 2, 0);
    __builtin_amdgcn_s_setprio(1);
    mfma8(acc[0], acc[1], a0, a1, bfr);
    __builtin_amdgcn_s_setprio(0);
    __builtin_amdgcn_s_barrier();
    // ---- phase 1: A m2-3; stage A-unit1; mfma m2-3
    a0 = *(const bf16x8*)(smem + bb + aOff + 2 * 1024);
    a1 = *(const bf16x8*)(smem + bb + aOff + 3 * 1024);
    if (st) stage_u(t + 2, 1);
    __builtin_amdgcn_s_setprio(1);
    mfma8(acc[2], acc[3], a0, a1, bfr);
    __builtin_amdgcn_s_setprio(0);
    __builtin_amdgcn_s_barrier();
    // ---- phase 2: A m4-5; stage B-unit0; mfma m4-5
    a0 = *(const bf16x8*)(smem + bb + aOff + 4 * 1024);
    a1 = *(const bf16x8*)(smem + bb + aOff + 5 * 1024);
    if (st) stage_u(t + 2, 2);
    __builtin_amdgcn_s_setprio(1);
    mfma8(acc[4], acc[5], a0, a1, bfr);
    __builtin_amdgcn_s_setprio(0);
    __builtin_amdgcn_s_barrier();
    // ---- phase 3: A m6-7; stage B-unit1; mfma m6-7 (no end barrier; next tile-top has one)
    a0 = *(const bf16x8*)(smem + bb + aOff + 6 * 1024);
    a1 = *(const bf16x8*)(smem + bb + aOff + 7 * 1024);
    if (st) stage_u(t + 2, 3);
    __builtin_amdgcn_s_setprio(1);
    mfma8(acc[6], acc[7], a0, a1, bfr);
    __builtin_amdgcn_s_setprio(0);
  }

  // epilogue
  const int r0 = mt * 256 + wr * 128 + (lane >> 4) * 4;
  const int c0e = nt * 256 + wc * 64 + l15;
#pragma unroll
  for (int m = 0; m < 8; ++m)
#pragma unroll
    for (int n = 0; n < 4; ++n)
#pragma unroll
      for (int j = 0; j < 4; ++j)
        C[(size_t)(r0 + m * 16 + j) * N + (c0e + n * 16)] = f2bf(acc[m][n][j]);
}

// ---------------- small GEMM (final layer, N=128): 128x128 tile, BK=32, 4 waves ----------------
__global__ __launch_bounds__(256) void k_gemm_bt(
    const unsigned short* __restrict__ A, const unsigned short* __restrict__ Bt,
    unsigned short* __restrict__ C, int M, int N, int K) {
  __shared__ __align__(16) unsigned short As[128 * 32];
  __shared__ __align__(16) unsigned short Bs[128 * 32];
  const int ntc = N >> 7;
  const int mt = blockIdx.x / ntc;
  const int nt = blockIdx.x % ntc;
  const int t = threadIdx.x;
  const int w = t >> 6, lane = t & 63;
  const int wr = w >> 1, wc = w & 1;
  f32x4 acc[4][4] = {};
  const unsigned short* ga = A + (size_t)(mt * 128 + (t >> 2)) * K + (t & 3) * 8;
  const unsigned short* gb = Bt + (size_t)(nt * 128 + (t >> 2)) * K + (t & 3) * 8;
  unsigned short* lA = &As[w * 512];
  unsigned short* lB = &Bs[w * 512];
  const size_t rowskip = (size_t)64 * K;
  for (int kt = 0; kt < K; kt += 32) {
    gld16(ga + kt, lA);
    gld16(ga + kt + rowskip, lA + 2048);
    gld16(gb + kt, lB);
    gld16(gb + kt + rowskip, lB + 2048);
    __syncthreads();
    bf16x8 af[4], bfr[4];
#pragma unroll
    for (int m = 0; m < 4; ++m)
      af[m] = *(const bf16x8*)&As[(wr * 64 + m * 16 + (lane & 15)) * 32 + (lane >> 4) * 8];
#pragma unroll
    for (int n = 0; n < 4; ++n)
      bfr[n] = *(const bf16x8*)&Bs[(wc * 64 + n * 16 + (lane & 15)) * 32 + (lane >> 4) * 8];
#pragma unroll
    for (int m = 0; m < 4; ++m)
#pragma unroll
      for (int n = 0; n < 4; ++n)
        acc[m][n] = __builtin_amdgcn_mfma_f32_16x16x32_bf16(af[m], bfr[n], acc[m][n], 0, 0, 0);
    __syncthreads();
  }
  const int r0 = mt * 128 + wr * 64 + (lane >> 4) * 4;
  const int c0 = nt * 128 + wc * 64 + (lane & 15);
#pragma unroll
  for (int m = 0; m < 4; ++m)
#pragma unroll
    for (int n = 0; n < 4; ++n)
#pragma unroll
      for (int r = 0; r < 4; ++r)
        C[(size_t)(r0 + m * 16 + r) * N + (c0 + n * 16)] = f2bf(acc[m][n][r]);
}

// ---------------- SpMM + epilogue (512 feat): out = relu(sum val*s[col] + bias + res) ----------------
__global__ __launch_bounds__(256) void k_spmm_ep512(
    const int* __restrict__ rowptr, const int* __restrict__ scol, const float* __restrict__ sval,
    const unsigned short* __restrict__ s, int sStride,
    const unsigned short* __restrict__ res, int resStride,
    const float* __restrict__ bias,
    unsigned short* __restrict__ o, int oStride, int nReal, int nTot) {
  int gw = (blockIdx.x * 256 + threadIdx.x) >> 6;
  int lane = threadIdx.x & 63;
  if (gw >= nTot) return;
  unsigned short* op = o + (size_t)gw * oStride + lane * 8;
  if (gw >= nReal) {  // keep pad rows zero for next GEMM's A reads
    *(ushort8*)op = (ushort8){0,0,0,0,0,0,0,0};
    return;
  }
  float acc[8] = {0.f,0.f,0.f,0.f,0.f,0.f,0.f,0.f};
  int e0 = rowptr[gw], e1 = rowptr[gw + 1];
  for (int e = e0; e < e1; ++e) {
    int c = scol[e];
    float v = sval[e];
    ushort8 svv = *(const ushort8*)(s + (size_t)c * sStride + lane * 8);
#pragma unroll
    for (int k = 0; k < 8; ++k) acc[k] += v * bf2f(svv[k]);
  }
  ushort8 rv = *(const ushort8*)(res + (size_t)gw * resStride + lane * 8);
  ushort8 ov;
#pragma unroll
  for (int k = 0; k < 8; ++k) {
    float tt = acc[k] + bias[lane * 8 + k] + bf2f(rv[k]);
    ov[k] = f2bf(fmaxf(tt, 0.f));
  }
  *(ushort8*)op = ov;
}

// ---------------- final: 64-wide SpMM + bias + res + relu + log_softmax ----------------
__global__ __launch_bounds__(256) void k_spmm_lsm(
    const int* __restrict__ rowptr, const int* __restrict__ scol, const float* __restrict__ sval,
    const unsigned short* __restrict__ g2, const float* __restrict__ bias2,
    float* __restrict__ out, int n) {
  int gw = (blockIdx.x * 256 + threadIdx.x) >> 6;
  int lane = threadIdx.x & 63;
  if (gw >= n) return;
  int e0 = rowptr[gw], e1 = rowptr[gw + 1];
  float acc = 0.f;
  for (int e = e0; e < e1; ++e) {
    int c = scol[e];
    acc += sval[e] * bf2f(g2[(size_t)c * 128 + lane]);
  }
  float t = acc + bias2[lane] + bf2f(g2[(size_t)gw * 128 + 64 + lane]);
  float v = fmaxf(t, 0.f);
  float m = v;
#pragma unroll
  for (int o = 32; o > 0; o >>= 1) m = fmaxf(m, __shfl_xor(m, o));
  float ex = __expf(v - m);
  float ss = ex;
#pragma unroll
  for (int o = 32; o > 0; o >>= 1) ss += __shfl_xor(ss, o);
  out[(size_t)gw * 64 + lane] = v - m - __logf(ss);
}

// ---------------- launch ----------------
extern "C" void kernel_launch(void* const* d_in, const int* in_sizes, int n_in,
                              void* d_out, int out_size, void* d_ws, size_t ws_size,
                              hipStream_t stream) {
  const float* x    = (const float*)d_in[0];
  const int*   arow = (const int*)d_in[1];
  const int*   acol = (const int*)d_in[2];
  const float* aval = (const float*)d_in[3];
  const float* W1   = (const float*)d_in[4];
  const float* b1   = (const float*)d_in[5];
  const float* p1W  = (const float*)d_in[6];
  const float* p1b  = (const float*)d_in[7];
  const float* W3   = (const float*)d_in[8];
  const float* b3   = (const float*)d_in[9];
  const float* W2   = (const float*)d_in[10];
  const float* b2   = (const float*)d_in[11];
  const float* p2W  = (const float*)d_in[12];
  const float* p2b  = (const float*)d_in[13];
  float* out = (float*)d_out;

  char* wsp = (char*)d_ws;
  size_t off = 0;
  auto take = [&](size_t bytes) -> char* {
    char* p = wsp + off;
    off = (off + bytes + 255) & ~(size_t)255;
    return p;
  };
  unsigned short* xb  = (unsigned short*)take((size_t)MP * 1024 * 2);
  unsigned short* g1  = (unsigned short*)take((size_t)MP * 1024 * 2);
  unsigned short* B1t = (unsigned short*)take((size_t)1024 * 1024 * 2);
  unsigned short* W3t = (unsigned short*)take((size_t)512 * 512 * 2);
  unsigned short* B2t = (unsigned short*)take((size_t)128 * 512 * 2);
  float* bias1 = (float*)take(512 * 4);
  float* bias2 = (float*)take(64 * 4);
  int*   cnt    = (int*)take((size_t)NNODES * 4);   // reused as cursor
  int*   rowptr = (int*)take((size_t)(NNODES + 1) * 4);
  int*   bsum   = (int*)take(256 * 4);
  int*   boff   = (int*)take(256 * 4);
  int*   scol   = (int*)take((size_t)NEDGES * 4);
  float* sval   = (float*)take((size_t)NEDGES * 4);
  unsigned short* h  = xb;  // alias: xb dead after GEMM1
  unsigned short* s  = g1;  // alias: g1 dead after layer-1 SpMM
  unsigned short* g2 = g1;  // alias: s dead after last L3 SpMM

  // CSR build
  hipMemsetAsync(cnt, 0, (size_t)NNODES * 4, stream);
  k_hist<<<(NEDGES + 255) / 256, 256, 0, stream>>>(arow, cnt, NEDGES);
  k_block_reduce<<<NB_SCAN, 256, 0, stream>>>(cnt, bsum, NNODES);
  k_scan_bsum<<<1, 256, 0, stream>>>(bsum, boff, NB_SCAN, rowptr, NNODES, NEDGES);
  k_block_scan<<<NB_SCAN, 256, 0, stream>>>(cnt, boff, rowptr, cnt, NNODES);
  k_scatter<<<(NEDGES + 255) / 256, 256, 0, stream>>>(arow, acol, aval, cnt, scol, sval, NEDGES);

  // pack inputs
  k_cast_x<<<(int)(((size_t)MP * 1024 / 8 + 255) / 256), 256, 0, stream>>>(x, xb, NNODES);
  k_packT<<<dim3(1024 / 32, 512 / 32), dim3(32, 8), 0, stream>>>(W1, 1024, 512, 512, B1t, 0);
  k_packT<<<dim3(1024 / 32, 512 / 32), dim3(32, 8), 0, stream>>>(p1W, 1024, 512, 512, B1t, 512);
  k_packT<<<dim3(512 / 32, 512 / 32), dim3(32, 8), 0, stream>>>(W3, 512, 512, 512, W3t, 0);
  k_packT<<<dim3(512 / 32, 64 / 32), dim3(32, 8), 0, stream>>>(W2, 512, 64, 64, B2t, 0);
  k_packT<<<dim3(512 / 32, 64 / 32), dim3(32, 8), 0, stream>>>(p2W, 512, 64, 64, B2t, 64);
  k_pack_bias<<<1, 512, 0, stream>>>(b1, p1b, b2, p2b, bias1, bias2);

  // layer 1: g1 = [x@W1 | x@p1W] ; h = relu(spmm + b1 + res + p1b)
  k_gemm256<<<196 * 4, 512, 98304, stream>>>(xb, B1t, g1, MP, 1024, 1024);
  k_spmm_ep512<<<MP / 4, 256, 0, stream>>>(rowptr, scol, sval, g1, 1024, g1 + 512, 1024,
                                           bias1, h, 512, NNODES, MP);
  // 4 x gc3 (shared W3): s = h@W3 ; h = relu(spmm + b3 + h)
  for (int i = 0; i < 4; ++i) {
    k_gemm256<<<196 * 2, 512, 98304, stream>>>(h, W3t, s, MP, 512, 512);
    k_spmm_ep512<<<MP / 4, 256, 0, stream>>>(rowptr, scol, sval, s, 512, h, 512,
                                             b3, h, 512, NNODES, MP);
  }
  // final: g2 = [h@W2 | h@p2W] ; out = log_softmax(relu(spmm + b2 + res + p2b))
  k_gemm_bt<<<MP / 128, 256, 0, stream>>>(h, B2t, g2, MP, 128, 512);
  k_spmm_lsm<<<(NNODES + 3) / 4, 256, 0, stream>>>(rowptr, scol, sval, g2, bias2, out, NNODES);
}

// Round 5
// 614.641 us; speedup vs baseline: 1.0514x; 1.0259x over previous
//
#include <hip/hip_runtime.h>

// ---------------- types / helpers ----------------
typedef __attribute__((ext_vector_type(8))) short bf16x8;           // MFMA A/B frag (8 bf16)
typedef __attribute__((ext_vector_type(8))) unsigned short ushort8; // 16B vector
typedef __attribute__((ext_vector_type(4))) float f32x4;            // MFMA C/D frag

#define NNODES 50000
#define NEDGES 160000
#define MP     50176   // 392*128 padded rows
#define NB_SCAN 196    // ceil(50000/256)

__device__ __forceinline__ float bf2f(unsigned short u) {
  return __uint_as_float(((unsigned int)u) << 16);
}
__device__ __forceinline__ unsigned short f2bf(float f) {
  unsigned int u = __float_as_uint(f);
  u += 0x7fffu + ((u >> 16) & 1u);   // RNE
  return (unsigned short)(u >> 16);
}
__device__ __forceinline__ void gld16(const void* g, void* l) {
  // async global->LDS, 16B per lane; LDS dest = wave-uniform base + lane*16
  __builtin_amdgcn_global_load_lds((__attribute__((address_space(1))) void*)g,
                                   (__attribute__((address_space(3))) void*)l, 16, 0, 0);
}

// ---------------- CSR build ----------------
__global__ void k_hist(const int* __restrict__ row, int* __restrict__ cnt, int n) {
  int i = blockIdx.x * 256 + threadIdx.x;
  if (i < n) atomicAdd(&cnt[row[i]], 1);
}

__global__ void k_block_reduce(const int* __restrict__ cnt, int* __restrict__ bsum, int n) {
  __shared__ int sd[256];
  int i = blockIdx.x * 256 + threadIdx.x;
  sd[threadIdx.x] = (i < n) ? cnt[i] : 0;
  __syncthreads();
  for (int o = 128; o > 0; o >>= 1) {
    if (threadIdx.x < o) sd[threadIdx.x] += sd[threadIdx.x + o];
    __syncthreads();
  }
  if (threadIdx.x == 0) bsum[blockIdx.x] = sd[0];
}

__global__ void k_scan_bsum(const int* __restrict__ bsum, int* __restrict__ boff, int nb,
                            int* __restrict__ rowptr, int n, int E) {
  __shared__ int sd[256];
  int v = (threadIdx.x < nb) ? bsum[threadIdx.x] : 0;
  sd[threadIdx.x] = v;
  __syncthreads();
  for (int o = 1; o < 256; o <<= 1) {
    int t = (threadIdx.x >= o) ? sd[threadIdx.x - o] : 0;
    __syncthreads();
    sd[threadIdx.x] += t;
    __syncthreads();
  }
  if (threadIdx.x < nb) boff[threadIdx.x] = sd[threadIdx.x] - v;  // exclusive
  if (threadIdx.x == 0) rowptr[n] = E;
}

__global__ void k_block_scan(const int* __restrict__ cnt, const int* __restrict__ boff,
                             int* __restrict__ rowptr, int* __restrict__ cursor, int n) {
  __shared__ int sd[256];
  int i = blockIdx.x * 256 + threadIdx.x;
  int v = (i < n) ? cnt[i] : 0;
  sd[threadIdx.x] = v;
  __syncthreads();
  for (int o = 1; o < 256; o <<= 1) {
    int t = (threadIdx.x >= o) ? sd[threadIdx.x - o] : 0;
    __syncthreads();
    sd[threadIdx.x] += t;
    __syncthreads();
  }
  if (i < n) {
    int r = boff[blockIdx.x] + sd[threadIdx.x] - v;  // exclusive
    rowptr[i] = r;
    cursor[i] = r;   // cursor aliases cnt; each thread reads its cnt before writing
  }
}

__global__ void k_scatter(const int* __restrict__ row, const int* __restrict__ col,
                          const float* __restrict__ val, int* __restrict__ cursor,
                          int* __restrict__ scol, float* __restrict__ sval, int n) {
  int e = blockIdx.x * 256 + threadIdx.x;
  if (e < n) {
    int p = atomicAdd(&cursor[row[e]], 1);
    scol[p] = col[e];
    sval[p] = val[e];
  }
}

// ---------------- packing ----------------
__global__ void k_cast_x(const float* __restrict__ x, unsigned short* __restrict__ xb, int nRealRows) {
  size_t idx = ((size_t)blockIdx.x * 256 + threadIdx.x) * 8;
  if (idx >= (size_t)MP * 1024) return;
  int row = (int)(idx >> 10);
  ushort8 o;
  if (row < nRealRows) {
    float4 a = *(const float4*)(x + idx);
    float4 b = *(const float4*)(x + idx + 4);
    o[0] = f2bf(a.x); o[1] = f2bf(a.y); o[2] = f2bf(a.z); o[3] = f2bf(a.w);
    o[4] = f2bf(b.x); o[5] = f2bf(b.y); o[6] = f2bf(b.z); o[7] = f2bf(b.w);
  } else {
    o = (ushort8){0,0,0,0,0,0,0,0};
  }
  *(ushort8*)(xb + idx) = o;
}

// dst[(dstOff+n)*K + k] = bf16(src[k*srcW + n])  (transpose-pack, K%32==0, nc%32==0)
__global__ void k_packT(const float* __restrict__ src, int K, int srcW, int nc,
                        unsigned short* __restrict__ dst, int dstOff) {
  __shared__ float tile[32][33];
  int k0 = blockIdx.x * 32, n0 = blockIdx.y * 32;
  int tx = threadIdx.x, ty = threadIdx.y;
  for (int i = ty; i < 32; i += 8)
    tile[i][tx] = src[(size_t)(k0 + i) * srcW + (n0 + tx)];
  __syncthreads();
  for (int i = ty; i < 32; i += 8)
    dst[(size_t)(dstOff + n0 + i) * K + (k0 + tx)] = f2bf(tile[tx][i]);
}

__global__ void k_pack_bias(const float* __restrict__ b1, const float* __restrict__ p1b,
                            const float* __restrict__ b2, const float* __restrict__ p2b,
                            float* __restrict__ bias1, float* __restrict__ bias2) {
  int t = threadIdx.x;
  bias1[t] = b1[t] + p1b[t];
  if (t < 64) bias2[t] = b2[t] + p2b[t];
}

// ---------------- big GEMM: 128x256 tile, BK=32, 3 LDS bufs, dist-2, 2 blocks/CU ----------------
// C[M,N](bf16) = A[M,K](bf16) @ Bt[N,K]^T, f32 accum. M%128==0, N%256==0, K%32==0, K/32>=3.
// LDS 72KB: buf t%3 (24KB) = A[128][32] @ +0, B[256][32] @ +8192; 16B chunks, chunk ^= (row>>1)&3.
// One barrier + one counted vmcnt(3) per K-tile; stage(t+2) cover = 2 tiles.
// __launch_bounds__(512,4) -> <=128 VGPR -> 2 blocks/CU (16 waves): cross-block overlap hides drains.
__global__ __launch_bounds__(512, 4) void k_gemm128x256(
    const unsigned short* __restrict__ A, const unsigned short* __restrict__ Bt,
    unsigned short* __restrict__ C, int M, int N, int K) {
  extern __shared__ char smem[];
  const int NT = N >> 8;
  // bijective XCD swizzle (m204)
  const int nwg = gridDim.x;
  const int q = nwg >> 3, r = nwg & 7;
  const int xcd = blockIdx.x & 7, local = blockIdx.x >> 3;
  const int swz = (xcd < r ? xcd * (q + 1) : r * (q + 1) + (xcd - r) * q) + local;
  const int mt = swz / NT, nt = swz % NT;

  const int tid = threadIdx.x;
  const int w = tid >> 6, lane = tid & 63;
  const int wr = w >> 2, wc = w & 3;            // 2M x 4N waves; wave tile 64 x 64

  // staging: A = 1 unit (128 rows x 64B = 8KB), B = 2 units. thread -> row tid>>2, chunk tid&3.
  const int srow = tid >> 2;
  const int schunk = (tid & 3) ^ ((tid >> 3) & 3);   // source chunk inverse-swizzled
  const unsigned short* gA = A + (size_t)(mt * 128 + srow) * K + schunk * 8;
  const unsigned short* gB = Bt + (size_t)(nt * 256 + srow) * K + schunk * 8;
  const size_t rs128 = (size_t)128 * K;
  const int wb = w << 10;   // wave-uniform LDS dest offset

  // ds_read bases: row = base + (lane&15), k-chunk = lane>>4, swizzled by (row>>1)&3
  const int l15 = lane & 15;
  const int cpos = ((lane >> 4) ^ ((l15 >> 1) & 3)) << 4;
  const int aOff = (wr * 64 + l15) * 64 + cpos;             // + m*1024
  const int bOff = 8192 + (wc * 64 + l15) * 64 + cpos;      // + n*1024

  f32x4 acc[4][4] = {};
  const int T = K >> 5;

  auto STAGE = [&](int t) {
    char* db = smem + (t % 3) * 24576 + wb;
    const unsigned short* a = gA + t * 32;
    const unsigned short* b = gB + t * 32;
    gld16(a, db);                 // A rows 0-127
    gld16(b, db + 8192);          // B rows 0-127
    gld16(b + rs128, db + 16384); // B rows 128-255
  };

  // prologue: tiles 0,1 staged (6 outstanding vm-ops)
  STAGE(0); STAGE(1);

  for (int t = 0; t < T; ++t) {
    if (t < T - 1) asm volatile("s_waitcnt vmcnt(3)" ::: "memory");
    else           asm volatile("s_waitcnt vmcnt(0)" ::: "memory");
    __builtin_amdgcn_s_barrier();
    __builtin_amdgcn_sched_barrier(0);   // pin stage below barrier (no hoist into prev tile)
    if (t + 2 < T) STAGE(t + 2);
    const int bb = (t % 3) * 24576;
    bf16x8 af[4];
#pragma unroll
    for (int m = 0; m < 4; ++m) af[m] = *(const bf16x8*)(smem + bb + aOff + m * 1024);
    __builtin_amdgcn_s_setprio(1);
#pragma unroll
    for (int n = 0; n < 4; ++n) {
      bf16x8 bfr = *(const bf16x8*)(smem + bb + bOff + n * 1024);
#pragma unroll
      for (int m = 0; m < 4; ++m)
        acc[m][n] = __builtin_amdgcn_mfma_f32_16x16x32_bf16(af[m], bfr, acc[m][n], 0, 0, 0);
    }
    __builtin_amdgcn_s_setprio(0);
  }

  // epilogue: wave writes 64x64
  const int r0 = mt * 128 + wr * 64 + (lane >> 4) * 4;
  const int c0e = nt * 256 + wc * 64 + l15;
#pragma unroll
  for (int m = 0; m < 4; ++m)
#pragma unroll
    for (int n = 0; n < 4; ++n)
#pragma unroll
      for (int j = 0; j < 4; ++j)
        C[(size_t)(r0 + m * 16 + j) * N + (c0e + n * 16)] = f2bf(acc[m][n][j]);
}

// ---------------- small GEMM (final layer, N=128): 128x128 tile, BK=32, 4 waves ----------------
__global__ __launch_bounds__(256) void k_gemm_bt(
    const unsigned short* __restrict__ A, const unsigned short* __restrict__ Bt,
    unsigned short* __restrict__ C, int M, int N, int K) {
  __shared__ __align__(16) unsigned short As[128 * 32];
  __shared__ __align__(16) unsigned short Bs[128 * 32];
  const int ntc = N >> 7;
  const int mt = blockIdx.x / ntc;
  const int nt = blockIdx.x % ntc;
  const int t = threadIdx.x;
  const int w = t >> 6, lane = t & 63;
  const int wr = w >> 1, wc = w & 1;
  f32x4 acc[4][4] = {};
  const unsigned short* ga = A + (size_t)(mt * 128 + (t >> 2)) * K + (t & 3) * 8;
  const unsigned short* gb = Bt + (size_t)(nt * 128 + (t >> 2)) * K + (t & 3) * 8;
  unsigned short* lA = &As[w * 512];
  unsigned short* lB = &Bs[w * 512];
  const size_t rowskip = (size_t)64 * K;
  for (int kt = 0; kt < K; kt += 32) {
    gld16(ga + kt, lA);
    gld16(ga + kt + rowskip, lA + 2048);
    gld16(gb + kt, lB);
    gld16(gb + kt + rowskip, lB + 2048);
    __syncthreads();
    bf16x8 af[4], bfr[4];
#pragma unroll
    for (int m = 0; m < 4; ++m)
      af[m] = *(const bf16x8*)&As[(wr * 64 + m * 16 + (lane & 15)) * 32 + (lane >> 4) * 8];
#pragma unroll
    for (int n = 0; n < 4; ++n)
      bfr[n] = *(const bf16x8*)&Bs[(wc * 64 + n * 16 + (lane & 15)) * 32 + (lane >> 4) * 8];
#pragma unroll
    for (int m = 0; m < 4; ++m)
#pragma unroll
      for (int n = 0; n < 4; ++n)
        acc[m][n] = __builtin_amdgcn_mfma_f32_16x16x32_bf16(af[m], bfr[n], acc[m][n], 0, 0, 0);
    __syncthreads();
  }
  const int r0 = mt * 128 + wr * 64 + (lane >> 4) * 4;
  const int c0 = nt * 128 + wc * 64 + (lane & 15);
#pragma unroll
  for (int m = 0; m < 4; ++m)
#pragma unroll
    for (int n = 0; n < 4; ++n)
#pragma unroll
      for (int r = 0; r < 4; ++r)
        C[(size_t)(r0 + m * 16 + r) * N + (c0 + n * 16)] = f2bf(acc[m][n][r]);
}

// ---------------- SpMM + epilogue (512 feat): out = relu(sum val*s[col] + bias + res) ----------------
__global__ __launch_bounds__(256) void k_spmm_ep512(
    const int* __restrict__ rowptr, const int* __restrict__ scol, const float* __restrict__ sval,
    const unsigned short* __restrict__ s, int sStride,
    const unsigned short* __restrict__ res, int resStride,
    const float* __restrict__ bias,
    unsigned short* __restrict__ o, int oStride, int nReal, int nTot) {
  int gw = (blockIdx.x * 256 + threadIdx.x) >> 6;
  int lane = threadIdx.x & 63;
  if (gw >= nTot) return;
  unsigned short* op = o + (size_t)gw * oStride + lane * 8;
  if (gw >= nReal) {  // keep pad rows zero for next GEMM's A reads
    *(ushort8*)op = (ushort8){0,0,0,0,0,0,0,0};
    return;
  }
  float acc[8] = {0.f,0.f,0.f,0.f,0.f,0.f,0.f,0.f};
  int e0 = rowptr[gw], e1 = rowptr[gw + 1];
  for (int e = e0; e < e1; ++e) {
    int c = scol[e];
    float v = sval[e];
    ushort8 svv = *(const ushort8*)(s + (size_t)c * sStride + lane * 8);
#pragma unroll
    for (int k = 0; k < 8; ++k) acc[k] += v * bf2f(svv[k]);
  }
  ushort8 rv = *(const ushort8*)(res + (size_t)gw * resStride + lane * 8);
  ushort8 ov;
#pragma unroll
  for (int k = 0; k < 8; ++k) {
    float tt = acc[k] + bias[lane * 8 + k] + bf2f(rv[k]);
    ov[k] = f2bf(fmaxf(tt, 0.f));
  }
  *(ushort8*)op = ov;
}

// ---------------- final: 64-wide SpMM + bias + res + relu + log_softmax ----------------
__global__ __launch_bounds__(256) void k_spmm_lsm(
    const int* __restrict__ rowptr, const int* __restrict__ scol, const float* __restrict__ sval,
    const unsigned short* __restrict__ g2, const float* __restrict__ bias2,
    float* __restrict__ out, int n) {
  int gw = (blockIdx.x * 256 + threadIdx.x) >> 6;
  int lane = threadIdx.x & 63;
  if (gw >= n) return;
  int e0 = rowptr[gw], e1 = rowptr[gw + 1];
  float acc = 0.f;
  for (int e = e0; e < e1; ++e) {
    int c = scol[e];
    acc += sval[e] * bf2f(g2[(size_t)c * 128 + lane]);
  }
  float t = acc + bias2[lane] + bf2f(g2[(size_t)gw * 128 + 64 + lane]);
  float v = fmaxf(t, 0.f);
  float m = v;
#pragma unroll
  for (int o = 32; o > 0; o >>= 1) m = fmaxf(m, __shfl_xor(m, o));
  float ex = __expf(v - m);
  float ss = ex;
#pragma unroll
  for (int o = 32; o > 0; o >>= 1) ss += __shfl_xor(ss, o);
  out[(size_t)gw * 64 + lane] = v - m - __logf(ss);
}

// ---------------- launch ----------------
extern "C" void kernel_launch(void* const* d_in, const int* in_sizes, int n_in,
                              void* d_out, int out_size, void* d_ws, size_t ws_size,
                              hipStream_t stream) {
  const float* x    = (const float*)d_in[0];
  const int*   arow = (const int*)d_in[1];
  const int*   acol = (const int*)d_in[2];
  const float* aval = (const float*)d_in[3];
  const float* W1   = (const float*)d_in[4];
  const float* b1   = (const float*)d_in[5];
  const float* p1W  = (const float*)d_in[6];
  const float* p1b  = (const float*)d_in[7];
  const float* W3   = (const float*)d_in[8];
  const float* b3   = (const float*)d_in[9];
  const float* W2   = (const float*)d_in[10];
  const float* b2   = (const float*)d_in[11];
  const float* p2W  = (const float*)d_in[12];
  const float* p2b  = (const float*)d_in[13];
  float* out = (float*)d_out;

  char* wsp = (char*)d_ws;
  size_t off = 0;
  auto take = [&](size_t bytes) -> char* {
    char* p = wsp + off;
    off = (off + bytes + 255) & ~(size_t)255;
    return p;
  };
  unsigned short* xb  = (unsigned short*)take((size_t)MP * 1024 * 2);
  unsigned short* g1  = (unsigned short*)take((size_t)MP * 1024 * 2);
  unsigned short* B1t = (unsigned short*)take((size_t)1024 * 1024 * 2);
  unsigned short* W3t = (unsigned short*)take((size_t)512 * 512 * 2);
  unsigned short* B2t = (unsigned short*)take((size_t)128 * 512 * 2);
  float* bias1 = (float*)take(512 * 4);
  float* bias2 = (float*)take(64 * 4);
  int*   cnt    = (int*)take((size_t)NNODES * 4);   // reused as cursor
  int*   rowptr = (int*)take((size_t)(NNODES + 1) * 4);
  int*   bsum   = (int*)take(256 * 4);
  int*   boff   = (int*)take(256 * 4);
  int*   scol   = (int*)take((size_t)NEDGES * 4);
  float* sval   = (float*)take((size_t)NEDGES * 4);
  unsigned short* h  = xb;  // alias: xb dead after GEMM1
  unsigned short* s  = g1;  // alias: g1 dead after layer-1 SpMM
  unsigned short* g2 = g1;  // alias: s dead after last L3 SpMM

  // CSR build
  hipMemsetAsync(cnt, 0, (size_t)NNODES * 4, stream);
  k_hist<<<(NEDGES + 255) / 256, 256, 0, stream>>>(arow, cnt, NEDGES);
  k_block_reduce<<<NB_SCAN, 256, 0, stream>>>(cnt, bsum, NNODES);
  k_scan_bsum<<<1, 256, 0, stream>>>(bsum, boff, NB_SCAN, rowptr, NNODES, NEDGES);
  k_block_scan<<<NB_SCAN, 256, 0, stream>>>(cnt, boff, rowptr, cnt, NNODES);
  k_scatter<<<(NEDGES + 255) / 256, 256, 0, stream>>>(arow, acol, aval, cnt, scol, sval, NEDGES);

  // pack inputs
  k_cast_x<<<(int)(((size_t)MP * 1024 / 8 + 255) / 256), 256, 0, stream>>>(x, xb, NNODES);
  k_packT<<<dim3(1024 / 32, 512 / 32), dim3(32, 8), 0, stream>>>(W1, 1024, 512, 512, B1t, 0);
  k_packT<<<dim3(1024 / 32, 512 / 32), dim3(32, 8), 0, stream>>>(p1W, 1024, 512, 512, B1t, 512);
  k_packT<<<dim3(512 / 32, 512 / 32), dim3(32, 8), 0, stream>>>(W3, 512, 512, 512, W3t, 0);
  k_packT<<<dim3(512 / 32, 64 / 32), dim3(32, 8), 0, stream>>>(W2, 512, 64, 64, B2t, 0);
  k_packT<<<dim3(512 / 32, 64 / 32), dim3(32, 8), 0, stream>>>(p2W, 512, 64, 64, B2t, 64);
  k_pack_bias<<<1, 512, 0, stream>>>(b1, p1b, b2, p2b, bias1, bias2);

  // layer 1: g1 = [x@W1 | x@p1W] ; h = relu(spmm + b1 + res + p1b)
  k_gemm128x256<<<392 * 4, 512, 73728, stream>>>(xb, B1t, g1, MP, 1024, 1024);
  k_spmm_ep512<<<MP / 4, 256, 0, stream>>>(rowptr, scol, sval, g1, 1024, g1 + 512, 1024,
                                           bias1, h, 512, NNODES, MP);
  // 4 x gc3 (shared W3): s = h@W3 ; h = relu(spmm + b3 + h)
  for (int i = 0; i < 4; ++i) {
    k_gemm128x256<<<392 * 2, 512, 73728, stream>>>(h, W3t, s, MP, 512, 512);
    k_spmm_ep512<<<MP / 4, 256, 0, stream>>>(rowptr, scol, sval, s, 512, h, 512,
                                             b3, h, 512, NNODES, MP);
  }
  // final: g2 = [h@W2 | h@p2W] ; out = log_softmax(relu(spmm + b2 + res + p2b))
  k_gemm_bt<<<MP / 128, 256, 0, stream>>>(h, B2t, g2, MP, 128, 512);
  k_spmm_lsm<<<(NNODES + 3) / 4, 256, 0, stream>>>(rowptr, scol, sval, g2, bias2, out, NNODES);
}